// Round 7
// baseline (102.792 us; speedup 1.0000x reference)
//
#include <hip/hip_runtime.h>

// B=2, T=8192, C=64 retention attention, gamma=0.96875, GroupNorm(8), output (B,C,T)-flat.
// fp32 in/out. Sliding window of 17 64-wide s-chunks (gamma^1024 ~ 7.6e-15 << 2% threshold).
// R7: R6 structure (1 block/16-row tile, 4 waves split chunk window, 4 blocks/CU) +
// hardened wave-private sS roundtrip: explicit s_waitcnt lgkmcnt(0) + same-type b128
// reads. R6's post-timing divergence matched a DS write->read overtake under contention.
// mfma_f32_16x16x32_f16 layouts (R4/R5-validated):
//   A: m=lane&15, k=(lane>>4)*8+j   B: n=lane&15, k=(lane>>4)*8+j
//   C/D: col(n)=lane&15, row(m)=(lane>>4)*4+reg

constexpr int SEQ = 8192;
constexpr int CH  = 64;
constexpr float LOG2G = -0.045803690f;   // log2(0.96875)

typedef __attribute__((ext_vector_type(8))) _Float16     half8;
typedef __attribute__((ext_vector_type(4))) float        f32x4;
typedef __attribute__((ext_vector_type(4))) unsigned int u32x4;

__device__ inline unsigned short f2h(float x) {
    _Float16 h = (_Float16)x;
    return __builtin_bit_cast(unsigned short, h);
}

// ---------------------------------------------------------------------------
// Kernel 1: QKV projection via MFMA (R5-validated, unchanged).
// ---------------------------------------------------------------------------
__global__ __launch_bounds__(256) void qkv_kernel(
    const float* __restrict__ Xin, const float* __restrict__ Wq,
    const float* __restrict__ Wk, const float* __restrict__ Wv,
    unsigned short* __restrict__ Qh, unsigned short* __restrict__ Kh,
    unsigned short* __restrict__ Vt)
{
    __shared__ unsigned short sWt[3][64][72];
    const int tid = threadIdx.x;
    const size_t row0 = (size_t)blockIdx.x * 64;
    const int b  = (int)(row0 >> 13);
    const int t0 = (int)(row0 & (SEQ - 1));

    {   // stage W^T fp16
        const int c  = tid & 63;
        const int k0 = (tid >> 6) * 2;
        #pragma unroll
        for (int m = 0; m < 3; ++m) {
            const float* W = (m == 0) ? Wq : ((m == 1) ? Wk : Wv);
            #pragma unroll
            for (int it = 0; it < 8; ++it) {
                const int k = k0 + it * 8;
                const unsigned lo = f2h(W[k * 64 + c]);
                const unsigned hi = f2h(W[(k + 1) * 64 + c]);
                *(unsigned int*)&sWt[m][c][k] = lo | (hi << 16);
            }
        }
    }

    const int l15 = tid & 15, q4 = (tid >> 4) & 3, wvi = tid >> 6;

    half8 xf[2];
    {
        const float* Xp = Xin + (row0 + (size_t)(wvi * 16 + l15)) * 64;
        #pragma unroll
        for (int h = 0; h < 2; ++h) {
            const f32x4 a  = *(const f32x4*)(Xp + h * 32 + q4 * 8);
            const f32x4 bb = *(const f32x4*)(Xp + h * 32 + q4 * 8 + 4);
            half8 t;
            t[0] = (_Float16)a[0];  t[1] = (_Float16)a[1];
            t[2] = (_Float16)a[2];  t[3] = (_Float16)a[3];
            t[4] = (_Float16)bb[0]; t[5] = (_Float16)bb[1];
            t[6] = (_Float16)bb[2]; t[7] = (_Float16)bb[3];
            xf[h] = t;
        }
    }
    __syncthreads();

    const int trow = (int)row0 + wvi * 16;
    #pragma unroll
    for (int m = 0; m < 2; ++m) {
        unsigned short* O = (m == 0) ? Qh : Kh;
        #pragma unroll
        for (int ct = 0; ct < 4; ++ct) {
            const half8 wf0 = *(const half8*)&sWt[m][ct * 16 + l15][q4 * 8];
            const half8 wf1 = *(const half8*)&sWt[m][ct * 16 + l15][32 + q4 * 8];
            f32x4 d = {0.f, 0.f, 0.f, 0.f};
            d = __builtin_amdgcn_mfma_f32_16x16x32_f16(xf[0], wf0, d, 0, 0, 0);
            d = __builtin_amdgcn_mfma_f32_16x16x32_f16(xf[1], wf1, d, 0, 0, 0);
            #pragma unroll
            for (int i = 0; i < 4; ++i)
                O[(size_t)(trow + q4 * 4 + i) * 64 + ct * 16 + l15] = f2h(d[i]);
        }
    }
    #pragma unroll
    for (int mt = 0; mt < 4; ++mt) {
        const half8 wf0 = *(const half8*)&sWt[2][mt * 16 + l15][q4 * 8];
        const half8 wf1 = *(const half8*)&sWt[2][mt * 16 + l15][32 + q4 * 8];
        f32x4 d = {0.f, 0.f, 0.f, 0.f};
        d = __builtin_amdgcn_mfma_f32_16x16x32_f16(wf0, xf[0], d, 0, 0, 0);
        d = __builtin_amdgcn_mfma_f32_16x16x32_f16(wf1, xf[1], d, 0, 0, 0);
        #pragma unroll
        for (int i = 0; i < 4; ++i)
            Vt[(size_t)(b * 64 + mt * 16 + q4 * 4 + i) * SEQ + t0 + wvi * 16 + l15] = f2h(d[i]);
    }
}

// ---------------------------------------------------------------------------
// Kernel 2: one block per 16-row tile; 4 waves split the 17-chunk window.
// ---------------------------------------------------------------------------
__global__ __launch_bounds__(256, 4) void attn_kernel(
    const unsigned short* __restrict__ Qh, const unsigned short* __restrict__ Kh,
    const unsigned short* __restrict__ Vt,
    const float* __restrict__ gnw, const float* __restrict__ gnb,
    float* __restrict__ out)
{
    __shared__ unsigned int sS[4][16][44];       // per-wave S roundtrip (u32-typed)
    __shared__ float sO[4][16][68];              // per-wave fp32 partials
    __shared__ float sGW[64], sGB[64];

    const int tid  = threadIdx.x;
    const int w    = tid >> 6;
    const int lane = tid & 63;
    const int l15  = lane & 15, q4 = lane >> 4;
    const int tile = blockIdx.x;                 // 0..1023
    const int b    = tile >> 9;
    const int t0   = (tile & 511) << 4;

    if (tid < 64) { sGW[tid] = gnw[tid]; sGB[tid] = gnb[tid]; }

    const unsigned short* Qp = Qh + (size_t)(b * SEQ + t0 + l15) * 64 + q4 * 8;
    const half8 qf0 = *(const half8*)Qp;
    const half8 qf1 = *(const half8*)(Qp + 32);

    // decay: gamma^(t-s) = gbase * g0[i] * c16^st, t=t0+l15, s=s0+st*16+q4*4+i
    float g0[4];
    #pragma unroll
    for (int i = 0; i < 4; ++i)
        g0[i] = exp2f((float)(l15 - q4 * 4 - i) * LOG2G);
    const float c16 = exp2f(-16.f * LOG2G);      // gamma^-16
    const float c32 = c16 * c16;
    const float c48 = c32 * c16;

    f32x4 acc[4];
    #pragma unroll
    for (int ct = 0; ct < 4; ++ct) acc[ct] = (f32x4){0.f, 0.f, 0.f, 0.f};

    const int cs_hi = t0 >> 6;
    const int cs_lo = (cs_hi >= 16) ? cs_hi - 16 : 0;
    const unsigned short* Kbase = Kh + (size_t)b * SEQ * 64;
    const unsigned short* Vbase = Vt + (size_t)b * 64 * SEQ;

    for (int cs = cs_lo + w; cs <= cs_hi; cs += 4) {
        const int s0 = cs << 6;

        half8 kf[4][2];                          // K fragments (m = s)
        #pragma unroll
        for (int st = 0; st < 4; ++st) {
            const unsigned short* p = Kbase + (size_t)(s0 + st * 16 + l15) * 64 + q4 * 8;
            kf[st][0] = *(const half8*)p;
            kf[st][1] = *(const half8*)(p + 32);
        }
        f32x4 sv[4];                             // S^T = K . Q^T
        #pragma unroll
        for (int st = 0; st < 4; ++st) {
            f32x4 s = {0.f, 0.f, 0.f, 0.f};
            s = __builtin_amdgcn_mfma_f32_16x16x32_f16(kf[st][0], qf0, s, 0, 0, 0);
            s = __builtin_amdgcn_mfma_f32_16x16x32_f16(kf[st][1], qf1, s, 0, 0, 0);
            sv[st] = s;
        }

        half8 vf[4][2];                          // V^T fragments (n = c, k = s)
        #pragma unroll
        for (int ct = 0; ct < 4; ++ct) {
            const unsigned short* p = Vbase + (size_t)(ct * 16 + l15) * SEQ + s0 + q4 * 8;
            vf[ct][0] = *(const half8*)p;
            vf[ct][1] = *(const half8*)(p + 32);
        }

        const float gbase = exp2f((float)(t0 - s0) * LOG2G);
        const float gs[4] = {gbase, gbase * c16, gbase * c32, gbase * c48};
        if (cs < cs_hi) {                        // fully causal: no mask
            #pragma unroll
            for (int st = 0; st < 4; ++st) {
                const unsigned u0 = (unsigned)f2h(sv[st][0] * (gs[st] * g0[0]))
                                  | ((unsigned)f2h(sv[st][1] * (gs[st] * g0[1])) << 16);
                const unsigned u1 = (unsigned)f2h(sv[st][2] * (gs[st] * g0[2]))
                                  | ((unsigned)f2h(sv[st][3] * (gs[st] * g0[3])) << 16);
                sS[w][l15][st * 8 + q4 * 2]     = u0;
                sS[w][l15][st * 8 + q4 * 2 + 1] = u1;
            }
        } else {                                 // diagonal chunk: per-element mask
            const int dbase = t0 + l15 - s0;
            #pragma unroll
            for (int st = 0; st < 4; ++st) {
                float wt[4];
                #pragma unroll
                for (int i = 0; i < 4; ++i) {
                    const int srel = st * 16 + q4 * 4 + i;
                    wt[i] = (dbase - srel >= 0) ? gs[st] * g0[i] : 0.f;
                }
                const unsigned u0 = (unsigned)f2h(sv[st][0] * wt[0])
                                  | ((unsigned)f2h(sv[st][1] * wt[1]) << 16);
                const unsigned u1 = (unsigned)f2h(sv[st][2] * wt[2])
                                  | ((unsigned)f2h(sv[st][3] * wt[3]) << 16);
                sS[w][l15][st * 8 + q4 * 2]     = u0;
                sS[w][l15][st * 8 + q4 * 2 + 1] = u1;
            }
        }

        // Drain the DS queue before reading back what this wave just wrote:
        // same-wave write->read ordering proved unreliable under contention (R6).
        asm volatile("s_waitcnt lgkmcnt(0)" ::: "memory");

        const u32x4 ua0 = *(const u32x4*)&sS[w][l15][q4 * 4];        // s = q4*8..+7
        const u32x4 ua1 = *(const u32x4*)&sS[w][l15][16 + q4 * 4];   // s = 32+q4*8..+7
        const half8 af0 = __builtin_bit_cast(half8, ua0);
        const half8 af1 = __builtin_bit_cast(half8, ua1);
        #pragma unroll
        for (int ct = 0; ct < 4; ++ct) {
            acc[ct] = __builtin_amdgcn_mfma_f32_16x16x32_f16(af0, vf[ct][0], acc[ct], 0, 0, 0);
            acc[ct] = __builtin_amdgcn_mfma_f32_16x16x32_f16(af1, vf[ct][1], acc[ct], 0, 0, 0);
        }
    }

    // ---- epilogue: reduce 4 partials, GroupNorm, transposed store ----
    #pragma unroll
    for (int ct = 0; ct < 4; ++ct) {
        #pragma unroll
        for (int i = 0; i < 4; ++i)
            sO[w][q4 * 4 + i][ct * 16 + l15] = acc[ct][i];    // D: row=t, col=c
    }
    __syncthreads();
    {
        const int r = tid >> 4, c4 = (tid & 15) * 4;
        f32x4 v = *(const f32x4*)&sO[0][r][c4];
        v += *(const f32x4*)&sO[1][r][c4];
        v += *(const f32x4*)&sO[2][r][c4];
        v += *(const f32x4*)&sO[3][r][c4];
        *(f32x4*)&sO[0][r][c4] = v;
    }
    __syncthreads();
    if (tid < 128) {                             // GN: 16 rows x 8 groups
        const int r = tid >> 3, g = tid & 7;
        float x[8];
        float s = 0.f, ss = 0.f;
        #pragma unroll
        for (int j = 0; j < 8; ++j) {
            x[j] = sO[0][r][g * 8 + j];
            s += x[j]; ss += x[j] * x[j];
        }
        const float mu  = s * 0.125f;
        const float var = ss * 0.125f - mu * mu;
        const float rs  = rsqrtf(var + 1e-6f);
        #pragma unroll
        for (int j = 0; j < 8; ++j) {
            const int c = g * 8 + j;
            sO[0][r][c] = (x[j] - mu) * rs * sGW[c] + sGB[c];
        }
    }
    __syncthreads();
    #pragma unroll
    for (int pass = 0; pass < 4; ++pass) {       // lanes t-contiguous: 64B segments
        const int c = pass * 16 + (tid >> 4);
        const int t = tid & 15;
        out[(size_t)(b * 64 + c) * SEQ + t0 + t] = sO[0][t][c];
    }
}

// ---------------------------------------------------------------------------
extern "C" void kernel_launch(void* const* d_in, const int* in_sizes, int n_in,
                              void* d_out, int out_size, void* d_ws, size_t ws_size,
                              hipStream_t stream)
{
    const float* Xin = (const float*)d_in[0];
    const float* Wq  = (const float*)d_in[1];
    const float* Wk  = (const float*)d_in[2];
    const float* Wv  = (const float*)d_in[3];
    const float* gnw = (const float*)d_in[4];
    const float* gnb = (const float*)d_in[5];

    const size_t NROW = (size_t)2 * SEQ;          // 16384
    unsigned short* Qh = (unsigned short*)d_ws;   // 2 MB each (fp16)
    unsigned short* Kh = Qh + NROW * CH;
    unsigned short* Vt = Kh + NROW * CH;

    qkv_kernel<<<dim3(256), dim3(256), 0, stream>>>(Xin, Wq, Wk, Wv, Qh, Kh, Vt);
    attn_kernel<<<dim3(1024), dim3(256), 0, stream>>>(Qh, Kh, Vt, gnw, gnb, (float*)d_out);
}